// Round 1
// 3227.757 us; speedup vs baseline: 1.0959x; 1.0959x over previous
//
#include <hip/hip_runtime.h>
#include <cstdint>
#include <cstddef>

#define E_CNT   262144
#define NNODES  50000
#define EMB     512
#define KD      1536
#define ND      2048
#define NG      64
#define XROWS   (NNODES + E_CNT)

typedef unsigned short u16;
typedef short  s8v __attribute__((ext_vector_type(8)));
typedef float  f4v __attribute__((ext_vector_type(4)));

// ---- workspace layout (bytes) ----
#define WS_XB   0u                      // XROWS*512 bf16           = 319,635,456
#define WS_WT   319635456u              // 2048*1536 bf16           =   6,291,456
#define WS_B1   325926912u              // 2048 f32
#define WS_W2   325935104u              // 2048 f32
#define WS_P    325943296u              // 16*E f32                 =  16,777,216
#define WS_END  342720512u

__device__ __forceinline__ u16 f2bf(float f) {
    union { float f; uint32_t u; } v; v.f = f;
    uint32_t u = v.u;
    return (u16)((u + 0x7FFFu + ((u >> 16) & 1u)) >> 16);
}

// ---------------- x -> bf16 ----------------
__global__ void cvt_x(const float* __restrict__ x, uint32_t* __restrict__ xb) {
    size_t i = ((size_t)blockIdx.x * 256 + threadIdx.x) * 8;
    float4 a = *(const float4*)(x + i);
    float4 b = *(const float4*)(x + i + 4);
    uint4 r;
    r.x = (uint32_t)f2bf(a.x) | ((uint32_t)f2bf(a.y) << 16);
    r.y = (uint32_t)f2bf(a.z) | ((uint32_t)f2bf(a.w) << 16);
    r.z = (uint32_t)f2bf(b.x) | ((uint32_t)f2bf(b.y) << 16);
    r.w = (uint32_t)f2bf(b.z) | ((uint32_t)f2bf(b.w) << 16);
    *(uint4*)((char*)xb + i * 2) = r;
}

// ------- W1e|W1f -> WT[n][k] bf16 (tiled transpose) -------
__global__ void prep_w(const float* __restrict__ W1e, const float* __restrict__ W1f,
                       u16* __restrict__ wt) {
    __shared__ float tile[32][33];
    int n0 = blockIdx.x * 32, k0 = blockIdx.y * 32;
    int tx = threadIdx.x & 31, ty = threadIdx.x >> 5;   // 32 x 8
#pragma unroll
    for (int i = 0; i < 4; ++i) {
        int k = k0 + ty + i * 8, n = n0 + tx;
        float v = (n < 1024) ? W1e[k * 1024 + n] : W1f[k * 1024 + (n - 1024)];
        tile[ty + i * 8][tx] = v;
    }
    __syncthreads();
#pragma unroll
    for (int i = 0; i < 4; ++i) {
        int nl = ty + i * 8, kl = tx;
        wt[(size_t)(n0 + nl) * KD + k0 + kl] = f2bf(tile[kl][nl]);
    }
}

__global__ void prep_small(const float* __restrict__ b1e, const float* __restrict__ b1f,
                           const float* __restrict__ W2e, const float* __restrict__ W2f,
                           float* __restrict__ b1c, float* __restrict__ w2c) {
    int n = blockIdx.x * 256 + threadIdx.x;  // 0..2047
    if (n < 1024) { b1c[n] = b1e[n]; w2c[n] = W2e[n]; }
    else          { b1c[n] = b1f[n - 1024]; w2c[n] = W2f[n - 1024]; }
}

// ---------------- fused GEMM + gelu + W2-reduce ----------------
// grid = (16 n-tiles, 2048 m-tiles), 256 threads.
// Double-buffered LDS (prefetch next K-tile before compute), XOR-swizzled
// tiles (pre-swizzled global source + swizzled ds_read), XCD-grouped blocks.
__global__ __launch_bounds__(256)
void gemm_mlp(const u16* __restrict__ xb, const u16* __restrict__ wt,
              const float* __restrict__ b1c, const float* __restrict__ w2c,
              const int* __restrict__ ei, float* __restrict__ P) {
    __shared__ u16 Al[2][128 * 64];   // [buf][row][64] ; row = 128B ; swizzled units
    __shared__ u16 Bl[2][128 * 64];
    __shared__ float part[128];

    // ---- XCD-grouping remap: dispatch order o = bx + 16*by ; XCD = o % 8.
    // mb = (o&7) + 8*(o>>7), nb = (o>>3)&15  -> all 16 nb-blocks of an mb on one XCD.
    const unsigned o = blockIdx.x + (blockIdx.y << 4);
    const int mb = (int)((o & 7u) + ((o >> 7) << 3));
    const int nb = (int)((o >> 3) & 15u);
    const int m0 = mb << 7;
    const int n0 = nb << 7;
    const int t  = threadIdx.x;
    const int l  = t & 63;
    const int w  = t >> 6;

    // staging assignment: thread covers rows {rbase+32i}, 16B unit `unit`
    const int rbase = t >> 3;           // 0..31
    const int unit  = t & 7;            // 0..7
    // swizzled source column: LDS physical slot (r,u) holds logical unit u^(r&7);
    // r&7 == rbase&7 for all 4 staged rows.
    const int sunit = (unit ^ (rbase & 7)) << 3;   // element offset within 64-elem row

    int srcs[4], dsts[4];
#pragma unroll
    for (int i = 0; i < 4; ++i) {
        int e = m0 + rbase + i * 32;
        srcs[i] = ei[e];
        dsts[i] = ei[E_CNT + e];
    }

    if (t < 128) part[t] = 0.0f;

    const int wm = (w & 1) << 6;        // wave tile origin in m
    const int wn = (w >> 1) << 6;       // wave tile origin in n

    // per-lane epilogue constants: n = n0 + wn + nf*16 + (l&15)
    float b1v[4], w2v[4];
#pragma unroll
    for (int nf = 0; nf < 4; ++nf) {
        int n = n0 + wn + nf * 16 + (l & 15);
        b1v[nf] = b1c[n];
        w2v[nf] = w2c[n];
    }

    f4v acc[4][4];
#pragma unroll
    for (int mf = 0; mf < 4; ++mf)
#pragma unroll
        for (int nf = 0; nf < 4; ++nf)
            acc[mf][nf] = (f4v){0.f, 0.f, 0.f, 0.f};

    // ---- staging: issue 8 global_load_lds into buffer `Ad/Bd` for K-tile kt ----
    auto stage = [&](u16* Ad, u16* Bd, int kt) {
        const int k0   = kt << 6;
        const int seg  = k0 >> 9;       // 0:src 1:dst 2:edge-token
        const int koff = k0 & 511;
#pragma unroll
        for (int i = 0; i < 4; ++i) {
            int row;
            if (seg == 0)      row = srcs[i];
            else if (seg == 1) row = dsts[i];
            else               row = NNODES + m0 + rbase + i * 32;
            const u16* g = xb + (size_t)row * EMB + koff + sunit;
            __builtin_amdgcn_global_load_lds(
                (const __attribute__((address_space(1))) void*)g,
                (__attribute__((address_space(3))) void*)(Ad + (i * 32 + w * 8) * 64),
                16, 0, 0);
        }
#pragma unroll
        for (int i = 0; i < 4; ++i) {
            int n = n0 + rbase + i * 32;
            const u16* g = wt + (size_t)n * KD + k0 + sunit;
            __builtin_amdgcn_global_load_lds(
                (const __attribute__((address_space(1))) void*)g,
                (__attribute__((address_space(3))) void*)(Bd + (i * 32 + w * 8) * 64),
                16, 0, 0);
        }
    };

    // read-side physical unit offsets (elements): logical unit = (ks<<2)|(l>>4);
    // fragment row&7 == l&7 for every mf/nf  -> same swizzle for A and B.
    const int po0 = (((l >> 4) ^ (l & 7)) << 3);
    const int po1 = (((4 | (l >> 4)) ^ (l & 7)) << 3);

    const int l15 = l & 15;

    // prologue: fill buffer 0
    stage(Al[0], Bl[0], 0);
    __syncthreads();                    // drains vmcnt, tile 0 ready

    int cur = 0;
    for (int kt = 0; kt < 24; ++kt) {
        if (kt < 23) stage(Al[cur ^ 1], Bl[cur ^ 1], kt + 1);  // prefetch next tile

        const u16* Ab = Al[cur];
        const u16* Bb = Bl[cur];
#pragma unroll
        for (int ks = 0; ks < 2; ++ks) {
            const int po = ks ? po1 : po0;
            s8v a[4], b[4];
#pragma unroll
            for (int mf = 0; mf < 4; ++mf)
                a[mf] = *(const s8v*)(Ab + (wm + mf * 16 + l15) * 64 + po);
#pragma unroll
            for (int nf = 0; nf < 4; ++nf)
                b[nf] = *(const s8v*)(Bb + (wn + nf * 16 + l15) * 64 + po);
            __builtin_amdgcn_s_setprio(1);
#pragma unroll
            for (int mf = 0; mf < 4; ++mf)
#pragma unroll
                for (int nf = 0; nf < 4; ++nf)
                    acc[mf][nf] = __builtin_amdgcn_mfma_f32_16x16x32_bf16(
                        a[mf], b[nf], acc[mf][nf], 0, 0, 0);
            __builtin_amdgcn_s_setprio(0);
        }
        __syncthreads();                // drains prefetch vmcnt; next tile ready
        cur ^= 1;
    }

    // ---- epilogue: bias + gelu(tanh) + *W2, reduce over this block's 128 cols ----
    // C layout: m = wm + mf*16 + (l>>4)*4 + r ; n = wn + nf*16 + (l&15)
#pragma unroll
    for (int mf = 0; mf < 4; ++mf) {
#pragma unroll
        for (int r = 0; r < 4; ++r) {
            float s = 0.f;
#pragma unroll
            for (int nf = 0; nf < 4; ++nf) {
                float h  = acc[mf][nf][r] + b1v[nf];
                float x2 = h * h;
                float pp = fmaf(x2, 0.044715f, 1.0f);
                float u2 = 1.5957691216f * h * pp;        // 2*sqrt(2/pi)*(h+0.044715h^3)
                float ex = __expf(-u2);
                float sg = __builtin_amdgcn_rcpf(1.0f + ex); // gelu = h*sigmoid(u2)
                s = fmaf(h * sg, w2v[nf], s);
            }
            s += __shfl_xor(s, 1);
            s += __shfl_xor(s, 2);
            s += __shfl_xor(s, 4);
            s += __shfl_xor(s, 8);
            if ((l & 15) == 0) {
                int m = wm + mf * 16 + ((l >> 4) << 2) + r;
                atomicAdd(&part[m], s);
            }
        }
    }
    __syncthreads();
    if (t < 128) P[(size_t)nb * E_CNT + m0 + t] = part[t];
}

// ---------------- finalize: per-edge scalars -> outputs ----------------
__global__ void finalize(const float* __restrict__ P, const int* __restrict__ ei,
                         const float* __restrict__ pos, const int* __restrict__ batch,
                         const float* __restrict__ b2e, const float* __restrict__ b2f,
                         float* __restrict__ out) {
    __shared__ float ebin[NG];
    int t = threadIdx.x;
    if (t < NG) ebin[t] = 0.f;
    __syncthreads();
    int e = blockIdx.x * 256 + t;

    float se = b2e[0], sf = b2f[0];
#pragma unroll
    for (int nb = 0; nb < 8; ++nb)  se += P[(size_t)nb * E_CNT + e];
#pragma unroll
    for (int nb = 8; nb < 16; ++nb) sf += P[(size_t)nb * E_CNT + e];

    int s = ei[e], d = ei[E_CNT + e];
    float vx = pos[3 * s]     - pos[3 * d];
    float vy = pos[3 * s + 1] - pos[3 * d + 1];
    float vz = pos[3 * s + 2] - pos[3 * d + 2];
    float nrm = sqrtf(vx * vx + vy * vy + vz * vz);
    float inv = sf / fmaxf(nrm, 1e-12f);
    atomicAdd(&out[NG + 3 * s],     vx * inv);
    atomicAdd(&out[NG + 3 * s + 1], vy * inv);
    atomicAdd(&out[NG + 3 * s + 2], vz * inv);
    atomicAdd(&ebin[batch[s]], se);

    __syncthreads();
    if (t < NG) {
        float v = ebin[t];
        if (v != 0.f) atomicAdd(&out[t], v);
    }
}

extern "C" void kernel_launch(void* const* d_in, const int* in_sizes, int n_in,
                              void* d_out, int out_size, void* d_ws, size_t ws_size,
                              hipStream_t stream) {
    const float* x    = (const float*)d_in[0];
    const float* pos  = (const float*)d_in[1];
    const float* W1e  = (const float*)d_in[2];
    const float* b1e  = (const float*)d_in[3];
    const float* W2e  = (const float*)d_in[4];
    const float* b2e  = (const float*)d_in[5];
    const float* W1f  = (const float*)d_in[6];
    const float* b1f  = (const float*)d_in[7];
    const float* W2f  = (const float*)d_in[8];
    const float* b2f  = (const float*)d_in[9];
    const int*  batch = (const int*)d_in[10];
    const int*  ei    = (const int*)d_in[11];
    float* out        = (float*)d_out;

    if (ws_size < (size_t)WS_END) return;  // workspace too small — fail loudly

    char* ws = (char*)d_ws;
    uint32_t* xb32 = (uint32_t*)(ws + WS_XB);
    u16*      xb   = (u16*)(ws + WS_XB);
    u16*      wt   = (u16*)(ws + WS_WT);
    float*    b1c  = (float*)(ws + WS_B1);
    float*    w2c  = (float*)(ws + WS_W2);
    float*    P    = (float*)(ws + WS_P);

    hipMemsetAsync(d_out, 0, (size_t)out_size * sizeof(float), stream);

    cvt_x<<<78036, 256, 0, stream>>>(x, xb32);                       // 159,817,728 / 8 / 256
    prep_w<<<dim3(64, 48), 256, 0, stream>>>(W1e, W1f, wt);
    prep_small<<<8, 256, 0, stream>>>(b1e, b1f, W2e, W2f, b1c, w2c);
    gemm_mlp<<<dim3(16, 2048), 256, 0, stream>>>(xb, wt, b1c, w2c, ei, P);
    finalize<<<1024, 256, 0, stream>>>(P, ei, pos, batch, b2e, b2f, out);
}